// Round 3
// baseline (175.608 us; speedup 1.0000x reference)
//
#include <hip/hip_runtime.h>

#define IMH 384
#define IMW 384
#define OH 378
#define OW 378
#define NB 64
#define SROWS 15          // output rows per strip
#define INROWS 21         // SROWS + 6, multiple of 7 for clean unroll
#define NSTRIP 26         // 26*15 = 390 >= 378

// One thread per column; walks down a 21-input-row strip.
// Horizontal 7-window sums from two 16B global loads per image per row
// (L1/L2-served halo reuse); vertical 7-window via register circular buffer.
// Round 3: SROWS 36->15 (704 -> 1664 blocks) to fix the 20.5% occupancy
// latency stall; __launch_bounds__(384,8) keeps VGPR<=64 for 8 waves/EU.
__global__ __launch_bounds__(384, 8) void ssim_kernel(
    const float* __restrict__ X, const float* __restrict__ Y,
    const float* __restrict__ data_range, float* __restrict__ acc)
{
    const int tid   = threadIdx.x;
    const int strip = blockIdx.x;
    const int b     = blockIdx.y;
    const int y0    = strip * SROWS;

    const float* __restrict__ Xb = X + b * (IMH * IMW);
    const float* __restrict__ Yb = Y + b * (IMH * IMW);

    const int  c      = tid;
    const int  cc     = min(c, OW - 1);   // clamp so loads never go OOB
    const bool cvalid = (c < OW);

    const float L     = data_range[b];
    const float C1    = (0.01f * L) * (0.01f * L);
    const float C2    = (0.03f * L) * (0.03f * L);
    const float inv49 = 1.0f / 49.0f;
    const float covn  = 49.0f / 48.0f;    // unbiased covariance correction

    // Circular history of horizontal sums (7 rows x 5 products) + running
    // vertical sums. All register-resident (indices static after unroll).
    float H[7][5];
    float V[5];
    #pragma unroll
    for (int k = 0; k < 7; ++k)
        #pragma unroll
        for (int p = 0; p < 5; ++p) H[k][p] = 0.f;
    #pragma unroll
    for (int p = 0; p < 5; ++p) V[p] = 0.f;

    float lsum = 0.f;

    for (int rb = 0; rb < INROWS; rb += 7) {
        #pragma unroll
        for (int k = 0; k < 7; ++k) {
            const int r  = rb + k;
            const int ri = min(y0 + r, IMH - 1);   // uniform (SGPR) row clamp
            const float* xr = Xb + ri * IMW + cc;
            const float* yr = Yb + ri * IMW + cc;

            // 7-wide window via two 16B loads per image (cols c..c+7).
            float xw[8], yw[8];
            __builtin_memcpy(&xw[0], xr, 16);       // cols c..c+3
            __builtin_memcpy(&xw[4], xr + 4, 16);   // cols c+4..c+7
            __builtin_memcpy(&yw[0], yr, 16);
            __builtin_memcpy(&yw[4], yr + 4, 16);

            float sx = 0.f, sy = 0.f, sxx = 0.f, sxy = 0.f, syy = 0.f;
            #pragma unroll
            for (int j = 0; j < 7; ++j) {
                sx += xw[j];
                sy += yw[j];
                sxx = fmaf(xw[j], xw[j], sxx);
                sxy = fmaf(xw[j], yw[j], sxy);
                syy = fmaf(yw[j], yw[j], syy);
            }

            H[k][0] = sx;  H[k][1] = sy;  H[k][2] = sxx;
            H[k][3] = sxy; H[k][4] = syy;
            V[0] += sx; V[1] += sy; V[2] += sxx; V[3] += sxy; V[4] += syy;
            // V now covers input rows [y0+r-6 .. y0+r] (older slots are 0)

            const int o = y0 + r - 6;               // output row
            if (r >= 6 && o < OH) {                 // uniform branch
                float ux   = V[0] * inv49;
                float uy   = V[1] * inv49;
                float uxux = ux * ux, uyuy = uy * uy, uxuy = ux * uy;
                float vx   = (V[2] * inv49 - uxux) * covn;
                float vy   = (V[4] * inv49 - uyuy) * covn;
                float vxy  = (V[3] * inv49 - uxuy) * covn;
                float N1 = fmaf(2.f, uxuy, C1);
                float N2 = fmaf(2.f, vxy, C2);
                float D1 = uxux + uyuy + C1;
                float D2 = vx + vy + C2;
                float sval = (N1 * N2) * __builtin_amdgcn_rcpf(D1 * D2);
                lsum += cvalid ? sval : 0.f;
            }

            // Retire row r-6 (slot (k+1)%7); pre-strip slots hold 0.
            const int kn = (k + 1) % 7;
            #pragma unroll
            for (int p = 0; p < 5; ++p) V[p] -= H[kn][p];
        }
    }

    // ---- Block reduction: wave64 shuffle -> LDS -> one atomic/block ----
    __shared__ float red[6];
    #pragma unroll
    for (int off = 32; off > 0; off >>= 1)
        lsum += __shfl_down(lsum, off, 64);
    if ((tid & 63) == 0) red[tid >> 6] = lsum;
    __syncthreads();
    if (tid == 0) {
        float bs = ((red[0] + red[1]) + (red[2] + red[3])) + (red[4] + red[5]);
        atomicAdd(acc, bs);
    }
}

__global__ void finalize_kernel(const float* __restrict__ acc,
                                float* __restrict__ out)
{
    out[0] = 1.0f - acc[0] * (1.0f / (float)(NB * OH * OW));
}

extern "C" void kernel_launch(void* const* d_in, const int* in_sizes, int n_in,
                              void* d_out, int out_size, void* d_ws, size_t ws_size,
                              hipStream_t stream) {
    const float* X  = (const float*)d_in[0];
    const float* Y  = (const float*)d_in[1];
    const float* dr = (const float*)d_in[2];
    float* out = (float*)d_out;
    float* acc = (float*)d_ws;

    hipMemsetAsync(acc, 0, sizeof(float), stream);

    dim3 grid(NSTRIP, NB);   // 26 x 64 = 1664 blocks
    dim3 block(384);         // one thread per column (6 waves)
    ssim_kernel<<<grid, block, 0, stream>>>(X, Y, dr, acc);
    finalize_kernel<<<1, 1, 0, stream>>>(acc, out);
}

// Round 4
// 142.587 us; speedup vs baseline: 1.2316x; 1.2316x over previous
//
#include <hip/hip_runtime.h>

#define IMH 384
#define IMW 384
#define OH 378
#define OW 378
#define NB 64
#define SROWS 15          // output rows per strip
#define INROWS 21         // SROWS + 6, multiple of 7 for clean unroll
#define NSTRIP 26         // 26*15 = 390 >= 378

// One thread per column; walks down a 21-input-row strip.
// Horizontal 7-window sums from two 16B global loads per image per row
// (L1/L2-served halo reuse); vertical 7-window via register circular buffer.
// Round 4: launch_bounds(384,4) — (384,8) forced VGPR 52->32 and spilled
// 77 MB to scratch (R3 regression). 52 VGPR already allows 8 waves/EU;
// the grid (1664 blocks, 6.5/CU) now supplies the parallelism.
__global__ __launch_bounds__(384, 4) void ssim_kernel(
    const float* __restrict__ X, const float* __restrict__ Y,
    const float* __restrict__ data_range, float* __restrict__ acc)
{
    const int tid   = threadIdx.x;
    const int strip = blockIdx.x;
    const int b     = blockIdx.y;
    const int y0    = strip * SROWS;

    const float* __restrict__ Xb = X + b * (IMH * IMW);
    const float* __restrict__ Yb = Y + b * (IMH * IMW);

    const int  c      = tid;
    const int  cc     = min(c, OW - 1);   // clamp so loads never go OOB
    const bool cvalid = (c < OW);

    const float L     = data_range[b];
    const float C1    = (0.01f * L) * (0.01f * L);
    const float C2    = (0.03f * L) * (0.03f * L);
    const float inv49 = 1.0f / 49.0f;
    const float covn  = 49.0f / 48.0f;    // unbiased covariance correction

    // Circular history of horizontal sums (7 rows x 5 products) + running
    // vertical sums. All register-resident (indices static after unroll).
    float H[7][5];
    float V[5];
    #pragma unroll
    for (int k = 0; k < 7; ++k)
        #pragma unroll
        for (int p = 0; p < 5; ++p) H[k][p] = 0.f;
    #pragma unroll
    for (int p = 0; p < 5; ++p) V[p] = 0.f;

    float lsum = 0.f;

    for (int rb = 0; rb < INROWS; rb += 7) {
        #pragma unroll
        for (int k = 0; k < 7; ++k) {
            const int r  = rb + k;
            const int ri = min(y0 + r, IMH - 1);   // uniform (SGPR) row clamp
            const float* xr = Xb + ri * IMW + cc;
            const float* yr = Yb + ri * IMW + cc;

            // 7-wide window via two 16B loads per image (cols c..c+7).
            float xw[8], yw[8];
            __builtin_memcpy(&xw[0], xr, 16);       // cols c..c+3
            __builtin_memcpy(&xw[4], xr + 4, 16);   // cols c+4..c+7
            __builtin_memcpy(&yw[0], yr, 16);
            __builtin_memcpy(&yw[4], yr + 4, 16);

            float sx = 0.f, sy = 0.f, sxx = 0.f, sxy = 0.f, syy = 0.f;
            #pragma unroll
            for (int j = 0; j < 7; ++j) {
                sx += xw[j];
                sy += yw[j];
                sxx = fmaf(xw[j], xw[j], sxx);
                sxy = fmaf(xw[j], yw[j], sxy);
                syy = fmaf(yw[j], yw[j], syy);
            }

            H[k][0] = sx;  H[k][1] = sy;  H[k][2] = sxx;
            H[k][3] = sxy; H[k][4] = syy;
            V[0] += sx; V[1] += sy; V[2] += sxx; V[3] += sxy; V[4] += syy;
            // V now covers input rows [y0+r-6 .. y0+r] (older slots are 0)

            const int o = y0 + r - 6;               // output row
            if (r >= 6 && o < OH) {                 // uniform branch
                float ux   = V[0] * inv49;
                float uy   = V[1] * inv49;
                float uxux = ux * ux, uyuy = uy * uy, uxuy = ux * uy;
                float vx   = (V[2] * inv49 - uxux) * covn;
                float vy   = (V[4] * inv49 - uyuy) * covn;
                float vxy  = (V[3] * inv49 - uxuy) * covn;
                float N1 = fmaf(2.f, uxuy, C1);
                float N2 = fmaf(2.f, vxy, C2);
                float D1 = uxux + uyuy + C1;
                float D2 = vx + vy + C2;
                float sval = (N1 * N2) * __builtin_amdgcn_rcpf(D1 * D2);
                lsum += cvalid ? sval : 0.f;
            }

            // Retire row r-6 (slot (k+1)%7); pre-strip slots hold 0.
            const int kn = (k + 1) % 7;
            #pragma unroll
            for (int p = 0; p < 5; ++p) V[p] -= H[kn][p];
        }
    }

    // ---- Block reduction: wave64 shuffle -> LDS -> one atomic/block ----
    __shared__ float red[6];
    #pragma unroll
    for (int off = 32; off > 0; off >>= 1)
        lsum += __shfl_down(lsum, off, 64);
    if ((tid & 63) == 0) red[tid >> 6] = lsum;
    __syncthreads();
    if (tid == 0) {
        float bs = ((red[0] + red[1]) + (red[2] + red[3])) + (red[4] + red[5]);
        atomicAdd(acc, bs);
    }
}

__global__ void finalize_kernel(const float* __restrict__ acc,
                                float* __restrict__ out)
{
    out[0] = 1.0f - acc[0] * (1.0f / (float)(NB * OH * OW));
}

extern "C" void kernel_launch(void* const* d_in, const int* in_sizes, int n_in,
                              void* d_out, int out_size, void* d_ws, size_t ws_size,
                              hipStream_t stream) {
    const float* X  = (const float*)d_in[0];
    const float* Y  = (const float*)d_in[1];
    const float* dr = (const float*)d_in[2];
    float* out = (float*)d_out;
    float* acc = (float*)d_ws;

    hipMemsetAsync(acc, 0, sizeof(float), stream);

    dim3 grid(NSTRIP, NB);   // 26 x 64 = 1664 blocks
    dim3 block(384);         // one thread per column (6 waves)
    ssim_kernel<<<grid, block, 0, stream>>>(X, Y, dr, acc);
    finalize_kernel<<<1, 1, 0, stream>>>(acc, out);
}

// Round 5
// 141.049 us; speedup vs baseline: 1.2450x; 1.0109x over previous
//
#include <hip/hip_runtime.h>

#define IMH 384
#define IMW 384
#define OH 378
#define OW 378
#define NB 64
#define SROWS 10           // output rows per strip
#define INROWS 16          // SROWS + 6 input rows
#define NSTRIP 38          // 38*10 = 380 >= 378
#define TILE_F (INROWS * IMW)   // 6144 floats per image tile (24576 B)
#define NWAVE 7
#define BLOCK (NWAVE * 64) // 448 threads; wave w owns output cols 58w..58w+57

// Round 5: LDS-staged, vertical-first sliding window, bpermute horizontal.
// R2/R4 plateaued at VALUBusy~33%: per-row chains of overlapping global
// loads (200-900cyc) with only ~2 rows of loads in flight. Now: contiguous
// float4 strip staging (one barrier), hot loop reads 2x ds_read_b32/row
// (constant offsets, 2-way bank alias = free), horizontal 7-sums shared
// across lanes via ds_bpermute on the LDS pipe.
__device__ __forceinline__ float bperm(int byte_addr, float v) {
    return __int_as_float(__builtin_amdgcn_ds_bpermute(byte_addr, __float_as_int(v)));
}

__global__ __launch_bounds__(BLOCK) void ssim_kernel(
    const float* __restrict__ X, const float* __restrict__ Y,
    const float* __restrict__ data_range, float* __restrict__ acc)
{
    __shared__ __align__(16) float lx[TILE_F];
    __shared__ __align__(16) float ly[TILE_F];
    __shared__ float red[NWAVE];

    const int tid   = threadIdx.x;
    const int strip = blockIdx.x;
    const int b     = blockIdx.y;
    const int y0    = strip * SROWS;

    const float* __restrict__ Xs = X + b * (IMH * IMW) + y0 * IMW;
    const float* __restrict__ Ys = Y + b * (IMH * IMW) + y0 * IMW;

    // floats actually present in this strip (last strip is short; the
    // unstaged tail rows only feed masked outputs)
    const int navail = (IMH - y0) * IMW;

    // ---- Stage: strip is CONTIGUOUS in global; flat float4 copy ----
    #pragma unroll
    for (int i = 0; i < 4; ++i) {            // 4*448 = 1792 >= 1536 slots
        int s = i * BLOCK + tid;             // float4 slot index
        if (s < TILE_F / 4) {
            int f = s * 4;
            if (f + 4 <= navail) {
                float4 vx = *(const float4*)(Xs + f);
                float4 vy = *(const float4*)(Ys + f);
                *(float4*)(lx + f) = vx;
                *(float4*)(ly + f) = vy;
            }
        }
    }
    __syncthreads();

    // ---- Compute: vertical-first per column, horizontal via bpermute ----
    const int w  = tid >> 6;                 // wave: 0..6
    const int l  = tid & 63;                 // lane
    const int cg = 58 * w + l;               // this lane's input column
    const int c  = min(cg, IMW - 1);         // clamp (dup data, masked out)
    const bool cvalid = (l < 58) && (cg < OW);

    // bpermute byte addresses (lane pulls from lane l+k; wrap is masked)
    const int a1 = ((l + 1) & 63) * 4;
    const int a2 = ((l + 2) & 63) * 4;
    const int a4 = ((l + 4) & 63) * 4;
    const int a6 = ((l + 6) & 63) * 4;

    const float L     = data_range[b];
    const float C1    = (0.01f * L) * (0.01f * L);
    const float C2    = (0.03f * L) * (0.03f * L);
    const float inv49 = 1.0f / 49.0f;
    const float covn  = 49.0f / 48.0f;

    float xh[7], yh[7];
    #pragma unroll
    for (int k = 0; k < 7; ++k) { xh[k] = 0.f; yh[k] = 0.f; }
    float V0 = 0.f, V1 = 0.f, V2 = 0.f, V3 = 0.f, V4 = 0.f;
    float lsum = 0.f;

    #pragma unroll
    for (int r = 0; r < INROWS; ++r) {
        const int ks = r % 7;                // static after full unroll
        float x  = lx[r * IMW + c];          // constant-offset ds_read_b32
        float y  = ly[r * IMW + c];
        float xo = xh[ks], yo = yh[ks];
        V0 += x - xo;
        V1 += y - yo;
        V2 += fmaf(x, x, -(xo * xo));
        V3 += fmaf(x, y, -(xo * yo));
        V4 += fmaf(y, y, -(yo * yo));
        xh[ks] = x; yh[ks] = y;

        const int o = y0 + r - 6;            // output row (uniform)
        if (r >= 6 && o < OH) {
            // horizontal 7-window sums over lanes l..l+6 (4 bperm + 4 add)
            float S[5];
            const float Vv[5] = {V0, V1, V2, V3, V4};
            #pragma unroll
            for (int p = 0; p < 5; ++p) {
                float v  = Vv[p];
                float b2 = v + bperm(a1, v);         // cols [l, l+1]
                float c4 = b2 + bperm(a2, b2);       // cols [l..l+3]
                S[p] = c4 + bperm(a4, b2) + bperm(a6, v);  // + [l+4,l+5] + [l+6]
            }
            float ux   = S[0] * inv49;
            float uy   = S[1] * inv49;
            float uxux = ux * ux, uyuy = uy * uy, uxuy = ux * uy;
            float vx   = (S[2] * inv49 - uxux) * covn;
            float vy   = (S[4] * inv49 - uyuy) * covn;
            float vxy  = (S[3] * inv49 - uxuy) * covn;
            float N1 = fmaf(2.f, uxuy, C1);
            float N2 = fmaf(2.f, vxy, C2);
            float D1 = uxux + uyuy + C1;
            float D2 = vx + vy + C2;
            float sval = (N1 * N2) * __builtin_amdgcn_rcpf(D1 * D2);
            lsum += cvalid ? sval : 0.f;
        }
    }

    // ---- Block reduction: wave64 shuffle -> LDS -> one atomic/block ----
    #pragma unroll
    for (int off = 32; off > 0; off >>= 1)
        lsum += __shfl_down(lsum, off, 64);
    if (l == 0) red[w] = lsum;
    __syncthreads();
    if (tid == 0) {
        float bs = 0.f;
        #pragma unroll
        for (int k = 0; k < NWAVE; ++k) bs += red[k];
        atomicAdd(acc, bs);
    }
}

__global__ void finalize_kernel(const float* __restrict__ acc,
                                float* __restrict__ out)
{
    out[0] = 1.0f - acc[0] * (1.0f / (float)(NB * OH * OW));
}

extern "C" void kernel_launch(void* const* d_in, const int* in_sizes, int n_in,
                              void* d_out, int out_size, void* d_ws, size_t ws_size,
                              hipStream_t stream) {
    const float* X  = (const float*)d_in[0];
    const float* Y  = (const float*)d_in[1];
    const float* dr = (const float*)d_in[2];
    float* out = (float*)d_out;
    float* acc = (float*)d_ws;

    hipMemsetAsync(acc, 0, sizeof(float), stream);

    dim3 grid(NSTRIP, NB);   // 38 x 64 = 2432 blocks
    dim3 block(BLOCK);       // 448 threads = 7 waves
    ssim_kernel<<<grid, block, 0, stream>>>(X, Y, dr, acc);
    finalize_kernel<<<1, 1, 0, stream>>>(acc, out);
}

// Round 6
// 133.616 us; speedup vs baseline: 1.3143x; 1.0556x over previous
//
#include <hip/hip_runtime.h>

#define IMH 384
#define IMW 384
#define OH 378
#define OW 378
#define NB 64
#define SROWS 15          // output rows per strip
#define INROWS 21         // SROWS + 6 input rows
#define NSTRIP 26         // 26*15 = 390 >= 378

// Round 6: R4 register-sliding structure + explicit depth-2 software
// pipeline on the global loads. R2/R4/R5 all plateaued ~60us with
// VALUBusy~30%: dependent memory chains, ~1.5 rows of loads in flight
// (R4 compiler chose 44 VGPR). Now: double-buffered row registers, row
// r+1's 4x16B loads issued before row r's compute, full unroll, no
// min-waves cap so the allocator can hold both rows (+pipeline) in regs.

struct Row { float4 x0, x1, y0, y1; };  // cols c..c+7 of X and Y

__device__ __forceinline__ Row load_row(const float* __restrict__ xr,
                                        const float* __restrict__ yr) {
    Row t;
    t.x0 = *(const float4*)(xr);
    t.x1 = *(const float4*)(xr + 4);
    t.y0 = *(const float4*)(yr);
    t.y1 = *(const float4*)(yr + 4);
    return t;
}

__global__ __launch_bounds__(384) void ssim_kernel(
    const float* __restrict__ X, const float* __restrict__ Y,
    const float* __restrict__ data_range, float* __restrict__ acc)
{
    const int tid   = threadIdx.x;
    const int strip = blockIdx.x;
    const int b     = blockIdx.y;
    const int y0    = strip * SROWS;

    const float* __restrict__ Xb = X + b * (IMH * IMW);
    const float* __restrict__ Yb = Y + b * (IMH * IMW);

    const int  c      = tid;
    const int  cc     = min(c, OW - 1);   // clamp so loads never go OOB
    const bool cvalid = (c < OW);

    const float L     = data_range[b];
    const float C1    = (0.01f * L) * (0.01f * L);
    const float C2    = (0.03f * L) * (0.03f * L);
    const float inv49 = 1.0f / 49.0f;
    const float covn  = 49.0f / 48.0f;    // unbiased covariance correction

    // Circular history of horizontal sums (7 rows x 5 products) + running
    // vertical sums. All register-resident (indices static after unroll).
    float H[7][5];
    float V[5];
    #pragma unroll
    for (int k = 0; k < 7; ++k)
        #pragma unroll
        for (int p = 0; p < 5; ++p) H[k][p] = 0.f;
    #pragma unroll
    for (int p = 0; p < 5; ++p) V[p] = 0.f;

    float lsum = 0.f;

    // ---- depth-2 pipelined row walk ----
    Row buf[2];
    {
        const int ri = min(y0, IMH - 1);
        buf[0] = load_row(Xb + ri * IMW + cc, Yb + ri * IMW + cc);
    }

    #pragma unroll
    for (int r = 0; r < INROWS; ++r) {
        const int cur = r & 1;
        const int nxt = cur ^ 1;

        // issue next row's loads before consuming current row
        if (r + 1 < INROWS) {
            const int ri = min(y0 + r + 1, IMH - 1);
            buf[nxt] = load_row(Xb + ri * IMW + cc, Yb + ri * IMW + cc);
        }

        const Row t = buf[cur];
        const float xw[8] = {t.x0.x, t.x0.y, t.x0.z, t.x0.w,
                             t.x1.x, t.x1.y, t.x1.z, t.x1.w};
        const float yw[8] = {t.y0.x, t.y0.y, t.y0.z, t.y0.w,
                             t.y1.x, t.y1.y, t.y1.z, t.y1.w};

        float sx = 0.f, sy = 0.f, sxx = 0.f, sxy = 0.f, syy = 0.f;
        #pragma unroll
        for (int j = 0; j < 7; ++j) {
            sx += xw[j];
            sy += yw[j];
            sxx = fmaf(xw[j], xw[j], sxx);
            sxy = fmaf(xw[j], yw[j], sxy);
            syy = fmaf(yw[j], yw[j], syy);
        }

        const int ks = r % 7;               // static after unroll
        H[ks][0] = sx;  H[ks][1] = sy;  H[ks][2] = sxx;
        H[ks][3] = sxy; H[ks][4] = syy;
        V[0] += sx; V[1] += sy; V[2] += sxx; V[3] += sxy; V[4] += syy;
        // V now covers input rows [y0+r-6 .. y0+r] (older slots are 0)

        const int o = y0 + r - 6;           // output row (uniform branch)
        if (r >= 6 && o < OH) {
            float ux   = V[0] * inv49;
            float uy   = V[1] * inv49;
            float uxux = ux * ux, uyuy = uy * uy, uxuy = ux * uy;
            float vx   = (V[2] * inv49 - uxux) * covn;
            float vy   = (V[4] * inv49 - uyuy) * covn;
            float vxy  = (V[3] * inv49 - uxuy) * covn;
            float N1 = fmaf(2.f, uxuy, C1);
            float N2 = fmaf(2.f, vxy, C2);
            float D1 = uxux + uyuy + C1;
            float D2 = vx + vy + C2;
            float sval = (N1 * N2) * __builtin_amdgcn_rcpf(D1 * D2);
            lsum += cvalid ? sval : 0.f;
        }

        // Retire row r-6 (slot (r+1)%7); pre-strip slots hold 0.
        const int kn = (r + 1) % 7;
        #pragma unroll
        for (int p = 0; p < 5; ++p) V[p] -= H[kn][p];
    }

    // ---- Block reduction: wave64 shuffle -> LDS -> one atomic/block ----
    __shared__ float red[6];
    #pragma unroll
    for (int off = 32; off > 0; off >>= 1)
        lsum += __shfl_down(lsum, off, 64);
    if ((tid & 63) == 0) red[tid >> 6] = lsum;
    __syncthreads();
    if (tid == 0) {
        float bs = ((red[0] + red[1]) + (red[2] + red[3])) + (red[4] + red[5]);
        atomicAdd(acc, bs);
    }
}

__global__ void finalize_kernel(const float* __restrict__ acc,
                                float* __restrict__ out)
{
    out[0] = 1.0f - acc[0] * (1.0f / (float)(NB * OH * OW));
}

extern "C" void kernel_launch(void* const* d_in, const int* in_sizes, int n_in,
                              void* d_out, int out_size, void* d_ws, size_t ws_size,
                              hipStream_t stream) {
    const float* X  = (const float*)d_in[0];
    const float* Y  = (const float*)d_in[1];
    const float* dr = (const float*)d_in[2];
    float* out = (float*)d_out;
    float* acc = (float*)d_ws;

    hipMemsetAsync(acc, 0, sizeof(float), stream);

    dim3 grid(NSTRIP, NB);   // 26 x 64 = 1664 blocks
    dim3 block(384);         // one thread per column (6 waves)
    ssim_kernel<<<grid, block, 0, stream>>>(X, Y, dr, acc);
    finalize_kernel<<<1, 1, 0, stream>>>(acc, out);
}

// Round 7
// 129.434 us; speedup vs baseline: 1.3567x; 1.0323x over previous
//
#include <hip/hip_runtime.h>

#define IMH 384
#define IMW 384
#define OH 378
#define OW 378
#define NB 64
#define SROWS 22
#define INROWS 28          // SROWS + 6 = 4*7 (clean circular unroll)
#define NSTRIP 18          // 18*22 = 396 >= 378
#define BLOCK 320          // 5 waves = 20 DPP groups of 16 lanes
#define GPB (BLOCK / 16)   // groups per block

// Round 7: horizontal 7-window sums via DPP row_shl (fused into v_add on
// the VALU pipe). R5 proved LDS-based horizontal is DS-pipe-throughput
// bound (~24 DS/row -> 53us); R6 proved 8-wide global windows are
// VMEM-latency bound (64 B/lane/row, compiler sinks prefetch at 44 VGPR).
// Now: lane loads ONLY its own column (8 B/row), vertical slide with raw
// 14-reg history, horizontal = 4 fused DPP adds per product. 16-lane DPP
// rows give 10 outputs/16 lanes (62% packing) - still wins on floor.

// a + (b shifted from lane l+K within the 16-lane DPP row); out-of-row
// lanes read 0 (bound_ctrl=true) - only feeds invalid outputs.
template <int CTRL>
__device__ __forceinline__ float dpp_add(float a, float b) {
    int m = __builtin_amdgcn_update_dpp(0, __float_as_int(b), CTRL, 0xf, 0xf, true);
    return a + __int_as_float(m);
}

// sum of v over lanes l..l+6 (valid for lane%16 <= 9)
__device__ __forceinline__ float hsum7(float v) {
    float s2 = dpp_add<0x101>(v, v);    // row_shl:1  -> cols [l, l+1]
    float s4 = dpp_add<0x102>(s2, s2);  // row_shl:2  -> cols [l..l+3]
    float t  = dpp_add<0x104>(s4, s2);  // row_shl:4  -> + [l+4, l+5]
    return dpp_add<0x106>(t, v);        // row_shl:6  -> + [l+6]
}

__global__ __launch_bounds__(BLOCK) void ssim_kernel(
    const float* __restrict__ X, const float* __restrict__ Y,
    const float* __restrict__ data_range, float* __restrict__ acc)
{
    const int tid = threadIdx.x;
    const int b   = blockIdx.z;
    const int y0  = blockIdx.y * SROWS;

    const float* __restrict__ Xb = X + b * (IMH * IMW);
    const float* __restrict__ Yb = Y + b * (IMH * IMW);

    const int j    = tid & 15;                       // lane within DPP row
    const int grp  = blockIdx.x * GPB + (tid >> 4);  // global 16-lane group
    const int c0   = grp * 10;                       // group's first output col
    const int col  = c0 + j;
    const int cin  = min(col, IMW - 1);              // clamped input col
    const bool cvalid = (j < 10) && (col < OW);

    const float L     = data_range[b];
    const float C1    = (0.01f * L) * (0.01f * L);
    const float C2    = (0.03f * L) * (0.03f * L);
    const float inv49 = 1.0f / 49.0f;
    const float covn  = 49.0f / 48.0f;

    // raw per-column 7-row history + running vertical sums (19 regs)
    float xh[7], yh[7];
    #pragma unroll
    for (int k = 0; k < 7; ++k) { xh[k] = 0.f; yh[k] = 0.f; }
    float V0 = 0.f, V1 = 0.f, V2 = 0.f, V3 = 0.f, V4 = 0.f;
    float lsum = 0.f;

    // depth-2 prefetch of the 2x4B column loads
    float xn = Xb[y0 * IMW + cin];
    float yn = Yb[y0 * IMW + cin];

    #pragma unroll
    for (int r = 0; r < INROWS; ++r) {
        const float x = xn, y = yn;
        if (r + 1 < INROWS) {
            const int ri = min(y0 + r + 1, IMH - 1);  // uniform row clamp
            xn = Xb[ri * IMW + cin];
            yn = Yb[ri * IMW + cin];
        }

        // vertical 7-row slide (raw history; recompute products on retire)
        const int ks = r % 7;                         // static after unroll
        const float xo = xh[ks], yo = yh[ks];
        V0 += x - xo;
        V1 += y - yo;
        V2 = fmaf(x, x, V2);  V2 = fmaf(-xo, xo, V2);
        V3 = fmaf(x, y, V3);  V3 = fmaf(-xo, yo, V3);
        V4 = fmaf(y, y, V4);  V4 = fmaf(-yo, yo, V4);
        xh[ks] = x; yh[ks] = y;

        const int o = y0 + r - 6;                     // output row (uniform)
        if (r >= 6 && o < OH) {
            const float S0 = hsum7(V0);
            const float S1 = hsum7(V1);
            const float S2 = hsum7(V2);
            const float S3 = hsum7(V3);
            const float S4 = hsum7(V4);
            float ux   = S0 * inv49;
            float uy   = S1 * inv49;
            float uxux = ux * ux, uyuy = uy * uy, uxuy = ux * uy;
            float vx   = (S2 * inv49 - uxux) * covn;
            float vy   = (S4 * inv49 - uyuy) * covn;
            float vxy  = (S3 * inv49 - uxuy) * covn;
            float N1 = fmaf(2.f, uxuy, C1);
            float N2 = fmaf(2.f, vxy, C2);
            float D1 = uxux + uyuy + C1;
            float D2 = vx + vy + C2;
            float sval = (N1 * N2) * __builtin_amdgcn_rcpf(D1 * D2);
            lsum += cvalid ? sval : 0.f;
        }
    }

    // ---- Block reduction: wave64 shuffle -> LDS -> one atomic/block ----
    __shared__ float red[BLOCK / 64];
    #pragma unroll
    for (int off = 32; off > 0; off >>= 1)
        lsum += __shfl_down(lsum, off, 64);
    if ((tid & 63) == 0) red[tid >> 6] = lsum;
    __syncthreads();
    if (tid == 0) {
        float bs = 0.f;
        #pragma unroll
        for (int k = 0; k < BLOCK / 64; ++k) bs += red[k];
        atomicAdd(acc, bs);
    }
}

__global__ void finalize_kernel(const float* __restrict__ acc,
                                float* __restrict__ out)
{
    out[0] = 1.0f - acc[0] * (1.0f / (float)(NB * OH * OW));
}

extern "C" void kernel_launch(void* const* d_in, const int* in_sizes, int n_in,
                              void* d_out, int out_size, void* d_ws, size_t ws_size,
                              hipStream_t stream) {
    const float* X  = (const float*)d_in[0];
    const float* Y  = (const float*)d_in[1];
    const float* dr = (const float*)d_in[2];
    float* out = (float*)d_out;
    float* acc = (float*)d_ws;

    hipMemsetAsync(acc, 0, sizeof(float), stream);

    dim3 grid(2, NSTRIP, NB);   // 2 x 18 x 64 = 2304 blocks
    dim3 block(BLOCK);          // 320 threads = 5 waves
    ssim_kernel<<<grid, block, 0, stream>>>(X, Y, dr, acc);
    finalize_kernel<<<1, 1, 0, stream>>>(acc, out);
}

// Round 8
// 121.285 us; speedup vs baseline: 1.4479x; 1.0672x over previous
//
#include <hip/hip_runtime.h>

#define IMH 384
#define IMW 384
#define OH 378
#define OW 378
#define NB 64
#define SROWS 18
#define INROWS 24          // SROWS + 6
#define NSTRIP 21          // 21*18 = 378 exactly
#define BLOCK 256          // 4 waves = 16 DPP groups of 16 lanes
#define GSTRIDE 26         // output cols per group (13 lanes x 2 cols)

// Round 8: 2 columns per lane. R7 (1 col/lane, 2-block col split) wasted
// 40% of lanes on clamped duplicates and packed only 10/16 DPP lanes.
// Now: one 256-thread block spans the full 384-col row (16 groups x 26
// output cols), lane j owns cols 26g+2j,+1 via one float2 load per image
// per row. Horizontal 7-window from pair sums: A=pp+shl1(pp)+shl2(pp);
// S_even=A+shl3(e); S_odd=A-e+shl3(pp) -> 6 ops/product/2 outputs.
// Even/odd lanes-worth of math expressed as float2 -> v_pk_* eligible.

template <int CTRL>
__device__ __forceinline__ float dpp_sh(float v) {
    return __int_as_float(__builtin_amdgcn_update_dpp(
        0, __float_as_int(v), CTRL, 0xf, 0xf, true));
}

__device__ __forceinline__ float2 f2add(float2 a, float2 b) { return make_float2(a.x + b.x, a.y + b.y); }
__device__ __forceinline__ float2 f2sub(float2 a, float2 b) { return make_float2(a.x - b.x, a.y - b.y); }
__device__ __forceinline__ float2 f2mul(float2 a, float2 b) { return make_float2(a.x * b.x, a.y * b.y); }
__device__ __forceinline__ float2 f2fma(float2 a, float2 b, float2 c) {
    return make_float2(fmaf(a.x, b.x, c.x), fmaf(a.y, b.y, c.y));
}
__device__ __forceinline__ float2 f2fnma(float2 a, float2 b, float2 c) {  // c - a*b
    return make_float2(fmaf(-a.x, b.x, c.x), fmaf(-a.y, b.y, c.y));
}
__device__ __forceinline__ float2 f2fms(float2 a, float s, float2 c) {    // a*s - c
    return make_float2(fmaf(a.x, s, -c.x), fmaf(a.y, s, -c.y));
}
__device__ __forceinline__ float2 f2s(float s) { return make_float2(s, s); }

__global__ __launch_bounds__(BLOCK) void ssim_kernel(
    const float* __restrict__ X, const float* __restrict__ Y,
    const float* __restrict__ data_range, float* __restrict__ acc)
{
    const int tid = threadIdx.x;
    const int b   = blockIdx.z;
    const int y0  = blockIdx.y * SROWS;

    const float* __restrict__ Xb = X + b * (IMH * IMW);
    const float* __restrict__ Yb = Y + b * (IMH * IMW);

    const int g   = tid >> 4;                 // DPP group 0..15
    const int j   = tid & 15;                 // lane within group
    const int ce  = g * GSTRIDE + 2 * j;      // lane's even column (global)
    const int cin = min(ce, IMW - 2);         // clamped, even -> 8B aligned
    const bool ve = (j <= 12) && (ce     < OW);
    const bool vo = (j <= 12) && (ce + 1 < OW);

    const float L     = data_range[b];
    const float C1    = (0.01f * L) * (0.01f * L);
    const float C2    = (0.03f * L) * (0.03f * L);
    const float inv49 = 1.0f / 49.0f;
    const float covn  = 49.0f / 48.0f;

    // per-lane raw history of its 2 columns + running vertical sums
    float2 xh[7], yh[7];
    #pragma unroll
    for (int k = 0; k < 7; ++k) { xh[k] = f2s(0.f); yh[k] = f2s(0.f); }
    float2 V0 = f2s(0.f), V1 = f2s(0.f), V2 = f2s(0.f),
           V3 = f2s(0.f), V4 = f2s(0.f);
    float lsum = 0.f;

    // depth-2 prefetch of the two 8B column loads
    float2 xn = *(const float2*)(Xb + y0 * IMW + cin);
    float2 yn = *(const float2*)(Yb + y0 * IMW + cin);

    #pragma unroll
    for (int r = 0; r < INROWS; ++r) {
        const float2 x = xn, y = yn;
        if (r + 1 < INROWS) {
            const int ri = min(y0 + r + 1, IMH - 1);   // uniform row clamp
            xn = *(const float2*)(Xb + ri * IMW + cin);
            yn = *(const float2*)(Yb + ri * IMW + cin);
        }

        // vertical 7-row slide on both columns (pk-f32 eligible)
        const int ks = r % 7;                          // static after unroll
        const float2 xo = xh[ks], yo = yh[ks];
        V0 = f2add(V0, f2sub(x, xo));
        V1 = f2add(V1, f2sub(y, yo));
        V2 = f2fma(x, x, V2);  V2 = f2fnma(xo, xo, V2);
        V3 = f2fma(x, y, V3);  V3 = f2fnma(xo, yo, V3);
        V4 = f2fma(y, y, V4);  V4 = f2fnma(yo, yo, V4);
        xh[ks] = x; yh[ks] = y;

        if (r >= 6) {   // output row o = y0+r-6; tiling guarantees o < OH
            // horizontal 7-window sums for even+odd output cols
            const float2 Vv[5] = {V0, V1, V2, V3, V4};
            float Se[5], So[5];
            #pragma unroll
            for (int p = 0; p < 5; ++p) {
                const float e  = Vv[p].x;
                const float pp = Vv[p].x + Vv[p].y;        // lane pair sum
                float A = pp + dpp_sh<0x101>(pp);          // pp(l)+pp(l+1)
                A      += dpp_sh<0x102>(pp);               // +pp(l+2)
                Se[p] = A + dpp_sh<0x103>(e);              // cols 2l..2l+6
                So[p] = (A - e) + dpp_sh<0x103>(pp);       // cols 2l+1..2l+7
            }
            const float2 S0 = make_float2(Se[0], So[0]);
            const float2 S1 = make_float2(Se[1], So[1]);
            const float2 S2 = make_float2(Se[2], So[2]);
            const float2 S3 = make_float2(Se[3], So[3]);
            const float2 S4 = make_float2(Se[4], So[4]);

            float2 ux   = f2mul(S0, f2s(inv49));
            float2 uy   = f2mul(S1, f2s(inv49));
            float2 uxux = f2mul(ux, ux);
            float2 uyuy = f2mul(uy, uy);
            float2 uxuy = f2mul(ux, uy);
            float2 vx   = f2mul(f2fms(S2, inv49, uxux), f2s(covn));
            float2 vy   = f2mul(f2fms(S4, inv49, uyuy), f2s(covn));
            float2 vxy  = f2mul(f2fms(S3, inv49, uxuy), f2s(covn));
            float2 N1   = f2fma(f2s(2.f), uxuy, f2s(C1));
            float2 N2   = f2fma(f2s(2.f), vxy, f2s(C2));
            float2 D1   = f2add(f2add(uxux, uyuy), f2s(C1));
            float2 D2   = f2add(f2add(vx, vy), f2s(C2));
            float2 num  = f2mul(N1, N2);
            float2 den  = f2mul(D1, D2);
            float  se   = num.x * __builtin_amdgcn_rcpf(den.x);
            float  so   = num.y * __builtin_amdgcn_rcpf(den.y);
            lsum += ve ? se : 0.f;
            lsum += vo ? so : 0.f;
        }
    }

    // ---- Block reduction: wave64 shuffle -> LDS -> one atomic/block ----
    __shared__ float red[BLOCK / 64];
    #pragma unroll
    for (int off = 32; off > 0; off >>= 1)
        lsum += __shfl_down(lsum, off, 64);
    if ((tid & 63) == 0) red[tid >> 6] = lsum;
    __syncthreads();
    if (tid == 0) {
        float bs = 0.f;
        #pragma unroll
        for (int k = 0; k < BLOCK / 64; ++k) bs += red[k];
        atomicAdd(acc, bs);
    }
}

__global__ void finalize_kernel(const float* __restrict__ acc,
                                float* __restrict__ out)
{
    out[0] = 1.0f - acc[0] * (1.0f / (float)(NB * OH * OW));
}

extern "C" void kernel_launch(void* const* d_in, const int* in_sizes, int n_in,
                              void* d_out, int out_size, void* d_ws, size_t ws_size,
                              hipStream_t stream) {
    const float* X  = (const float*)d_in[0];
    const float* Y  = (const float*)d_in[1];
    const float* dr = (const float*)d_in[2];
    float* out = (float*)d_out;
    float* acc = (float*)d_ws;

    hipMemsetAsync(acc, 0, sizeof(float), stream);

    dim3 grid(1, NSTRIP, NB);   // 21 x 64 = 1344 blocks
    dim3 block(BLOCK);          // 256 threads = 4 waves
    ssim_kernel<<<grid, block, 0, stream>>>(X, Y, dr, acc);
    finalize_kernel<<<1, 1, 0, stream>>>(acc, out);
}

// Round 9
// 116.663 us; speedup vs baseline: 1.5053x; 1.0396x over previous
//
#include <hip/hip_runtime.h>

#define IMH 384
#define IMW 384
#define OH 378
#define OW 378
#define NB 64
#define SROWS 18
#define INROWS 24          // SROWS + 6
#define NSTRIP 21          // 21*18 = 378 exactly
#define BLOCK 256          // 4 waves = 16 DPP groups of 16 lanes
#define GSTRIDE 26         // output cols per group (13 lanes x 2 cols)

// Round 9: R8 dataflow + amdgpu_waves_per_eu(4,4). R8's allocator squeezed
// to 32 VGPR (live set ~47) with zero spills -> it rematerialized history/
// prefetch via L1 re-loads and went latency-bound (VALUBusy 33%). Pinning
// 4 waves/EU gives a 128-VGPR budget and removes the incentive to shrink:
// history + depth-2 load pipeline stay register-resident.
// Also: validity as float2 mask folded into packed-FMA accumulator; one
// rcp per output row (se,so share rcp(dx*dy)).

template <int CTRL>
__device__ __forceinline__ float dpp_sh(float v) {
    return __int_as_float(__builtin_amdgcn_update_dpp(
        0, __float_as_int(v), CTRL, 0xf, 0xf, true));
}

__device__ __forceinline__ float2 f2add(float2 a, float2 b) { return make_float2(a.x + b.x, a.y + b.y); }
__device__ __forceinline__ float2 f2sub(float2 a, float2 b) { return make_float2(a.x - b.x, a.y - b.y); }
__device__ __forceinline__ float2 f2mul(float2 a, float2 b) { return make_float2(a.x * b.x, a.y * b.y); }
__device__ __forceinline__ float2 f2fma(float2 a, float2 b, float2 c) {
    return make_float2(fmaf(a.x, b.x, c.x), fmaf(a.y, b.y, c.y));
}
__device__ __forceinline__ float2 f2fnma(float2 a, float2 b, float2 c) {  // c - a*b
    return make_float2(fmaf(-a.x, b.x, c.x), fmaf(-a.y, b.y, c.y));
}
__device__ __forceinline__ float2 f2fms(float2 a, float s, float2 c) {    // a*s - c
    return make_float2(fmaf(a.x, s, -c.x), fmaf(a.y, s, -c.y));
}
__device__ __forceinline__ float2 f2s(float s) { return make_float2(s, s); }

__global__ __launch_bounds__(BLOCK)
__attribute__((amdgpu_waves_per_eu(4, 4)))
void ssim_kernel(
    const float* __restrict__ X, const float* __restrict__ Y,
    const float* __restrict__ data_range, float* __restrict__ acc)
{
    const int tid = threadIdx.x;
    const int b   = blockIdx.z;
    const int y0  = blockIdx.y * SROWS;

    const float* __restrict__ Xb = X + b * (IMH * IMW);
    const float* __restrict__ Yb = Y + b * (IMH * IMW);

    const int g   = tid >> 4;                 // DPP group 0..15
    const int j   = tid & 15;                 // lane within group
    const int ce  = g * GSTRIDE + 2 * j;      // lane's even column (global)
    const int cin = min(ce, IMW - 2);         // clamped, even -> 8B aligned
    const float2 vmask = make_float2(
        ((j <= 12) && (ce     < OW)) ? 1.f : 0.f,
        ((j <= 12) && (ce + 1 < OW)) ? 1.f : 0.f);

    const float L     = data_range[b];
    const float C1    = (0.01f * L) * (0.01f * L);
    const float C2    = (0.03f * L) * (0.03f * L);
    const float inv49 = 1.0f / 49.0f;
    const float covn  = 49.0f / 48.0f;

    // per-lane raw history of its 2 columns + running vertical sums
    float2 xh[7], yh[7];
    #pragma unroll
    for (int k = 0; k < 7; ++k) { xh[k] = f2s(0.f); yh[k] = f2s(0.f); }
    float2 V0 = f2s(0.f), V1 = f2s(0.f), V2 = f2s(0.f),
           V3 = f2s(0.f), V4 = f2s(0.f);
    float2 ls2 = f2s(0.f);

    // depth-2 explicit pipeline: rows r+1 and r+2 in flight
    float2 px[2], py[2];
    {
        const int r0 = min(y0,     IMH - 1);
        const int r1 = min(y0 + 1, IMH - 1);
        px[0] = *(const float2*)(Xb + r0 * IMW + cin);
        py[0] = *(const float2*)(Yb + r0 * IMW + cin);
        px[1] = *(const float2*)(Xb + r1 * IMW + cin);
        py[1] = *(const float2*)(Yb + r1 * IMW + cin);
    }

    #pragma unroll
    for (int r = 0; r < INROWS; ++r) {
        const int slot = r & 1;                        // static after unroll
        const float2 x = px[slot], y = py[slot];
        if (r + 2 < INROWS) {                          // refill consumed slot
            const int ri = min(y0 + r + 2, IMH - 1);   // uniform row clamp
            px[slot] = *(const float2*)(Xb + ri * IMW + cin);
            py[slot] = *(const float2*)(Yb + ri * IMW + cin);
        }

        // vertical 7-row slide on both columns (pk-f32 eligible)
        const int ks = r % 7;                          // static after unroll
        const float2 xo = xh[ks], yo = yh[ks];
        V0 = f2add(V0, f2sub(x, xo));
        V1 = f2add(V1, f2sub(y, yo));
        V2 = f2fma(x, x, V2);  V2 = f2fnma(xo, xo, V2);
        V3 = f2fma(x, y, V3);  V3 = f2fnma(xo, yo, V3);
        V4 = f2fma(y, y, V4);  V4 = f2fnma(yo, yo, V4);
        xh[ks] = x; yh[ks] = y;

        if (r >= 6) {   // output row o = y0+r-6; tiling guarantees o < OH
            // horizontal 7-window sums for even+odd output cols
            const float2 Vv[5] = {V0, V1, V2, V3, V4};
            float Se[5], So[5];
            #pragma unroll
            for (int p = 0; p < 5; ++p) {
                const float e  = Vv[p].x;
                const float pp = Vv[p].x + Vv[p].y;        // lane pair sum
                float A = pp + dpp_sh<0x101>(pp);          // pp(l)+pp(l+1)
                A      += dpp_sh<0x102>(pp);               // +pp(l+2)
                Se[p] = A + dpp_sh<0x103>(e);              // cols 2l..2l+6
                So[p] = (A - e) + dpp_sh<0x103>(pp);       // cols 2l+1..2l+7
            }
            const float2 S0 = make_float2(Se[0], So[0]);
            const float2 S1 = make_float2(Se[1], So[1]);
            const float2 S2 = make_float2(Se[2], So[2]);
            const float2 S3 = make_float2(Se[3], So[3]);
            const float2 S4 = make_float2(Se[4], So[4]);

            float2 ux   = f2mul(S0, f2s(inv49));
            float2 uy   = f2mul(S1, f2s(inv49));
            float2 uxux = f2mul(ux, ux);
            float2 uyuy = f2mul(uy, uy);
            float2 uxuy = f2mul(ux, uy);
            float2 vx   = f2mul(f2fms(S2, inv49, uxux), f2s(covn));
            float2 vy   = f2mul(f2fms(S4, inv49, uyuy), f2s(covn));
            float2 vxy  = f2mul(f2fms(S3, inv49, uxuy), f2s(covn));
            float2 N1   = f2fma(f2s(2.f), uxuy, f2s(C1));
            float2 N2   = f2fma(f2s(2.f), vxy, f2s(C2));
            float2 D1   = f2add(f2add(uxux, uyuy), f2s(C1));
            float2 D2   = f2add(f2add(vx, vy), f2s(C2));
            float2 num  = f2mul(N1, N2);
            float2 den  = f2mul(D1, D2);
            // one rcp for both columns: se = nx*dy/(dx*dy), so = ny*dx/(dx*dy)
            const float rdd = __builtin_amdgcn_rcpf(den.x * den.y);
            float2 s2 = make_float2(num.x * den.y * rdd,
                                    num.y * den.x * rdd);
            ls2 = f2fma(s2, vmask, ls2);
        }
    }

    float lsum = ls2.x + ls2.y;

    // ---- Block reduction: wave64 shuffle -> LDS -> one atomic/block ----
    __shared__ float red[BLOCK / 64];
    #pragma unroll
    for (int off = 32; off > 0; off >>= 1)
        lsum += __shfl_down(lsum, off, 64);
    if ((tid & 63) == 0) red[tid >> 6] = lsum;
    __syncthreads();
    if (tid == 0) {
        float bs = 0.f;
        #pragma unroll
        for (int k = 0; k < BLOCK / 64; ++k) bs += red[k];
        atomicAdd(acc, bs);
    }
}

__global__ void finalize_kernel(const float* __restrict__ acc,
                                float* __restrict__ out)
{
    out[0] = 1.0f - acc[0] * (1.0f / (float)(NB * OH * OW));
}

extern "C" void kernel_launch(void* const* d_in, const int* in_sizes, int n_in,
                              void* d_out, int out_size, void* d_ws, size_t ws_size,
                              hipStream_t stream) {
    const float* X  = (const float*)d_in[0];
    const float* Y  = (const float*)d_in[1];
    const float* dr = (const float*)d_in[2];
    float* out = (float*)d_out;
    float* acc = (float*)d_ws;

    hipMemsetAsync(acc, 0, sizeof(float), stream);

    dim3 grid(1, NSTRIP, NB);   // 21 x 64 = 1344 blocks
    dim3 block(BLOCK);          // 256 threads = 4 waves
    ssim_kernel<<<grid, block, 0, stream>>>(X, Y, dr, acc);
    finalize_kernel<<<1, 1, 0, stream>>>(acc, out);
}